// Round 12
// baseline (185.557 us; speedup 1.0000x reference)
//
#include <hip/hip_runtime.h>

#define T_SEQ 2048
#define N_B   4
#define N_H   16
#define D_H   64
#define EMB   1024
#define CSC   0.18033688011f  // log2(e) / sqrt(64), folded into Q at projection

typedef __attribute__((ext_vector_type(8))) short   vshort8;   // 8 bf16 (4 VGPRs)
typedef __attribute__((ext_vector_type(4))) float   vfloat4;   // 16x16 C/D
typedef __attribute__((ext_vector_type(16))) float  vfloat16;  // 32x32 C/D

__device__ __forceinline__ ushort f2bf(float f) {
  union { float f; unsigned u; } v; v.f = f;
  unsigned u = v.u;
  return (ushort)((u + 0x7fffu + ((u >> 16) & 1u)) >> 16);  // RNE
}
__device__ __forceinline__ unsigned pk2bf(float a, float b) {  // [bf(a),bf(b)] in mem
  return (unsigned)f2bf(a) | ((unsigned)f2bf(b) << 16);
}
__device__ __forceinline__ float bf2f(ushort b) {
  union { unsigned u; float f; } v; v.u = ((unsigned)b) << 16;
  return v.f;
}
__device__ __forceinline__ float fexp2(float x) {
#if __has_builtin(__builtin_amdgcn_exp2f)
  return __builtin_amdgcn_exp2f(x);
#else
  return exp2f(x);
#endif
}
// pack hi16(lo),hi16(hi) -> [bf_trunc(lo), bf_trunc(hi)] in memory (1 v_perm)
__device__ __forceinline__ unsigned permhi(float hi, float lo) {
  union { float f; unsigned u; } a, b; a.f = hi; b.f = lo;
#if __has_builtin(__builtin_amdgcn_perm)
  return __builtin_amdgcn_perm(a.u, b.u, 0x07060302u);
#else
  return (a.u & 0xFFFF0000u) | (b.u >> 16);
#endif
}
__device__ __forceinline__ vshort8 cvt8(const float* p) {
  float4 w0 = *(const float4*)(p);
  float4 w1 = *(const float4*)(p + 4);
  vshort8 t;
  t[0] = (short)f2bf(w0.x); t[1] = (short)f2bf(w0.y);
  t[2] = (short)f2bf(w0.z); t[3] = (short)f2bf(w0.w);
  t[4] = (short)f2bf(w1.x); t[5] = (short)f2bf(w1.y);
  t[6] = (short)f2bf(w1.z); t[7] = (short)f2bf(w1.w);
  return t;
}

// ---- 32-lane-fragment blob layouts (uint4 = 8 bf16 = one lane-frag) ----
// Q/K: uint4 idx = ((bh*64 + t32)*4 + dstep)*64 + l31*2 + h
//      lane (l31,h) frag = X[t = 32*t32 + l31][d = 16*dstep + 8*h + 0..7]
// V  : uint4 idx = (((bh*32 + s64)*4 + step)*2 + dblk)*64 + l31*2 + h
//      lane (l31,h) frag = V[s = 64*s64 + 16*step + 8*h + 0..7][d = 32*dblk + l31]

// ------- QKV projection (16x16 MFMA compute, 32-frag stores) ---------------
// Exactly round-9's version (best-total config, 172.1us).  W conversion
// fused in-kernel (r8: saved ~7.5us); r10 proved the uint2 store pattern
// is NOT a bottleneck (lane-permuted 8B stores coalesce at line level).
__global__ __launch_bounds__(256, 4) void proj_qkv(
    const float* __restrict__ x, const float* __restrict__ Wq,
    const float* __restrict__ Wk, const float* __restrict__ Wv,
    uint2* __restrict__ Qb, uint2* __restrict__ Kb, uint2* __restrict__ Vb) {
  const int wid  = threadIdx.x >> 6;
  const int lane = threadIdx.x & 63;
  const int l15  = lane & 15;
  const int q    = lane >> 4;
  const int gw    = blockIdx.x * 4 + wid;   // [0,8192)
  const int strip = gw >> 4;                // 16-row strip over B*T
  const int hd    = gw & 15;
  const int r0    = strip * 16;
  const int b     = r0 >> 11;
  const int bh    = b * N_H + hd;
  const int ts    = (r0 & (T_SEQ - 1)) >> 4;  // strip index within head [0,128)

  // ---- cooperative W conversion into LDS (layout == old Wb blob) ----
  __shared__ ushort Wl[24 * 64 * 8];   // 24 KB
#pragma unroll
  for (int fi = 0; fi < 6; ++fi) {
    const int f  = wid + fi * 4;             // frag group = (m*2+kc)*4+nt
    const int m  = f >> 3, kc = (f >> 2) & 1, nt = f & 3;
    const float* wsrc = (m == 0) ? Wq : (m == 1) ? Wk : Wv;
    vshort8 t = cvt8(wsrc + (nt * 16 + l15) * D_H + kc * 32 + q * 8);
    *(vshort8*)(&Wl[(f * 64 + lane) * 8]) = t;
  }

  // x frag: lane holds x[r0+l15][hd*64 + kc*32 + q*8 + j]
  vshort8 afr[2];
  {
    const float* xp = x + (size_t)(r0 + l15) * EMB + hd * D_H + q * 8;
    afr[0] = cvt8(xp);
    afr[1] = cvt8(xp + 32);
  }
  __syncthreads();                           // W fragments landed

  uint2* Bs[3] = {Qb, Kb, Vb};
#pragma unroll
  for (int m = 0; m < 3; ++m) {
    vshort8 wf[2][4];
#pragma unroll
    for (int kc = 0; kc < 2; ++kc)
#pragma unroll
      for (int nt = 0; nt < 4; ++nt)
        wf[kc][nt] = *(const vshort8*)(&Wl[(((m * 2 + kc) * 4 + nt) * 64 + lane) * 8]);
    vfloat4 acc[4];
#pragma unroll
    for (int nt = 0; nt < 4; ++nt) acc[nt] = (vfloat4){0.f, 0.f, 0.f, 0.f};
#pragma unroll
    for (int kc = 0; kc < 2; ++kc)
#pragma unroll
      for (int nt = 0; nt < 4; ++nt)
        acc[nt] = (m < 2)
          ? __builtin_amdgcn_mfma_f32_16x16x32_bf16(wf[kc][nt], afr[kc], acc[nt], 0, 0, 0)
          : __builtin_amdgcn_mfma_f32_16x16x32_bf16(afr[kc], wf[kc][nt], acc[nt], 0, 0, 0);
    uint2* B = Bs[m];
#pragma unroll
    for (int nt = 0; nt < 4; ++nt) {
      vfloat4 a = acc[nt];
      if (m == 0) { a[0] *= CSC; a[1] *= CSC; a[2] *= CSC; a[3] *= CSC; }
      uint2 w;
      w.x = pk2bf(a[0], a[1]);
      w.y = pk2bf(a[2], a[3]);
      size_t idx;
      if (m < 2) {
        // swapped C: lane holds (d = 16nt+4q+r, t = l15); t32 = ts>>1
        idx = ((size_t)(bh * 64 + (ts >> 1)) * 4 + nt) * 128
              + (l15 + 16 * (ts & 1)) * 4 + q;
      } else {
        // normal C: lane holds (s = 16(ts&3)+4q+r local in s64, d = 16nt+l15)
        idx = (((size_t)(bh * 32 + (ts >> 2)) * 4 + (ts & 3)) * 2 + (nt >> 1)) * 128
              + 64 * (nt & 1) + l15 * 4 + q;
      }
      B[idx] = w;
    }
  }
}

// ---------------- fused flash attention (no-max softmax) + V residual -------
// Round-9 attn (= round-0 inner loop: 83.5-84.9us, 124 VGPR, zero scratch,
// shfl_xor exchange) + SINGLE register-free addition: s_setprio(1)/(0)
// around the MFMA clusters (SOPP, zero register operands — cannot move
// VGPR pressure; r8/r11 spills are attributed to plswap's tied-operand
// asm, now permanently reverted).  m191: setprio +4-7% on attn in exactly
// this regime (independent blocks, no barriers, waves at different phases).
// Tripwire: VGPR != 124 or WRITE != 32768KB -> revert to r9 verbatim.
__global__ __launch_bounds__(256, 2) void attn_fused(
    const uint4* __restrict__ Qb, const uint4* __restrict__ Kb,
    const uint4* __restrict__ Vb, float* __restrict__ out) {
  const int tid  = threadIdx.x;
  const int wid  = tid >> 6;
  const int lane = tid & 63;
  const int l31  = lane & 31;
  const int h    = lane >> 5;

  // XCD swizzle: 16 consecutive per-XCD slots share a bh -> K/V stay in that L2
  const int blk  = blockIdx.x;                 // [0,512)
  const int work = (blk & 7) * 64 + (blk >> 3);
  const int bh   = work >> 3;
  const int tblk8 = work & 7;
  const int b = bh >> 4, hh = bh & 15;
  const int T64 = tblk8 * 4 + wid;             // this wave's 64-t chunk [0,32)

  const int lo = l31 * 2 + h;                  // lane offset in uint4 units

  // Q B-frags: lane holds Q[t = 32*t32 + l31][d = 16ds + 8h + j] * CSC
  vshort8 qf[2][4];
#pragma unroll
  for (int tb = 0; tb < 2; ++tb)
#pragma unroll
    for (int ds = 0; ds < 4; ++ds)
      qf[tb][ds] = *(const vshort8*)&Qb[((size_t)(bh * 64 + 2 * T64 + tb) * 4 + ds) * 64 + lo];

  vfloat16 oacc[2][2];
#pragma unroll
  for (int tb = 0; tb < 2; ++tb)
#pragma unroll
    for (int db = 0; db < 2; ++db)
#pragma unroll
      for (int i = 0; i < 16; ++i) oacc[tb][db][i] = 0.f;
  float lsum[2] = {0.f, 0.f};

#pragma unroll 1
  for (int ss = 0; ss < 32; ++ss) {  // 32 s-tiles of 64
    // K A-frags: lane holds K[s = 64ss + 32sb + l31][d = 16ds + 8h + j]
    vshort8 kf[2][4];
#pragma unroll
    for (int sb = 0; sb < 2; ++sb)
#pragma unroll
      for (int ds = 0; ds < 4; ++ds)
        kf[sb][ds] = *(const vshort8*)&Kb[((size_t)(bh * 64 + 2 * ss + sb) * 4 + ds) * 64 + lo];
    // V B-frags: lane holds V[s = 64ss + 16st + 8h + j][d = 32db + l31]
    vshort8 vf[4][2];
#pragma unroll
    for (int st = 0; st < 4; ++st)
#pragma unroll
      for (int db = 0; db < 2; ++db)
        vf[st][db] = *(const vshort8*)&Vb[(((size_t)(bh * 32 + ss) * 4 + st) * 2 + db) * 64 + lo];

#pragma unroll
    for (int tb = 0; tb < 2; ++tb) {
      // S^T = K*Q^T : C holds (s-local = (r&3)+8(r>>2)+4h + 32sb, t = l31)
      vfloat16 sacc[2];
#pragma unroll
      for (int sb = 0; sb < 2; ++sb) {
#pragma unroll
        for (int i = 0; i < 16; ++i) sacc[sb][i] = 0.f;
      }
      __builtin_amdgcn_s_setprio(1);
#pragma unroll
      for (int sb = 0; sb < 2; ++sb)
#pragma unroll
        for (int ds = 0; ds < 4; ++ds)
          sacc[sb] = __builtin_amdgcn_mfma_f32_32x32x16_bf16(kf[sb][ds], qf[tb][ds], sacc[sb], 0, 0, 0);
      __builtin_amdgcn_s_setprio(0);

      // no-max softmax + in-register C->A transpose of P
      float p[2][16];
      float ls = 0.f;
#pragma unroll
      for (int sb = 0; sb < 2; ++sb)
#pragma unroll
        for (int r = 0; r < 16; ++r) {
          p[sb][r] = fexp2(sacc[sb][r]);
          ls += p[sb][r];
        }
      lsum[tb] += ls;

#pragma unroll
      for (int sb = 0; sb < 2; ++sb)
#pragma unroll
        for (int g = 0; g < 2; ++g) {
          // own packs: OL = s 16g+4h+{0..3}, OH = s 16g+8+4h+{0..3} (local in sb)
          const unsigned OL0 = permhi(p[sb][8 * g + 1], p[sb][8 * g + 0]);
          const unsigned OL1 = permhi(p[sb][8 * g + 3], p[sb][8 * g + 2]);
          const unsigned OH0 = permhi(p[sb][8 * g + 5], p[sb][8 * g + 4]);
          const unsigned OH1 = permhi(p[sb][8 * g + 7], p[sb][8 * g + 6]);
          // exchange: h=0 needs partner's OL, h=1 needs partner's OH
          const unsigned s0 = h ? OL0 : OH0;
          const unsigned s1 = h ? OL1 : OH1;
          const unsigned r0 = (unsigned)__shfl_xor((int)s0, 32, 64);
          const unsigned r1 = (unsigned)__shfl_xor((int)s1, 32, 64);
          union { unsigned u[4]; vshort8 v; } pa;
          pa.u[0] = h ? r0 : OL0;
          pa.u[1] = h ? r1 : OL1;
          pa.u[2] = h ? OH0 : r0;
          pa.u[3] = h ? OH1 : r1;
          const int st = 2 * sb + g;
          __builtin_amdgcn_s_setprio(1);
#pragma unroll
          for (int db = 0; db < 2; ++db)
            oacc[tb][db] = __builtin_amdgcn_mfma_f32_32x32x16_bf16(pa.v, vf[st][db], oacc[tb][db], 0, 0, 0);
          __builtin_amdgcn_s_setprio(0);
        }
    }
  }

  // ---- epilogue: l-reduce, O/l + V residual ----
  const uint2* Vb2 = (const uint2*)Vb;
#pragma unroll
  for (int tb = 0; tb < 2; ++tb) {
    const float l = lsum[tb] + __shfl_xor(lsum[tb], 32, 64);
    const float inv = 1.0f / l;                // valid at t-local = l31
    const int T32 = 2 * T64 + tb;
#pragma unroll
    for (int db = 0; db < 2; ++db) {
#pragma unroll
      for (int rq = 0; rq < 4; ++rq) {
        const int sq = 8 * T32 + 2 * rq + h;   // t-quad (4 consecutive t)
        uint2 vr = Vb2[(((size_t)(bh * 32 + (sq >> 4)) * 4 + ((sq >> 2) & 3)) * 2 + db) * 128
                       + l31 * 4 + ((sq >> 1) & 1) * 2 + (sq & 1)];
        float vres[4];
        vres[0] = bf2f((ushort)(vr.x & 0xFFFFu));
        vres[1] = bf2f((ushort)(vr.x >> 16));
        vres[2] = bf2f((ushort)(vr.y & 0xFFFFu));
        vres[3] = bf2f((ushort)(vr.y >> 16));
#pragma unroll
        for (int rr = 0; rr < 4; ++rr) {
          const int row = rr + 8 * rq + 4 * h;          // t-local in [0,32)
          const float iT = __shfl(inv, row, 64);
          const int t = T32 * 32 + row;
          out[((size_t)(b * T_SEQ + t)) * EMB + hh * D_H + db * 32 + l31] =
              oacc[tb][db][rq * 4 + rr] * iT + vres[rr];
        }
      }
    }
  }
}

extern "C" void kernel_launch(void* const* d_in, const int* in_sizes, int n_in,
                              void* d_out, int out_size, void* d_ws, size_t ws_size,
                              hipStream_t stream) {
  const float* x  = (const float*)d_in[0];
  const float* Wq = (const float*)d_in[1];
  const float* Wk = (const float*)d_in[2];
  const float* Wv = (const float*)d_in[3];
  float* out = (float*)d_out;

  const size_t per4 = (size_t)64 * 64 * 4 * 64;  // 1,048,576 uint4 per blob (16 MB)
  uint4* Qb = (uint4*)d_ws;
  uint4* Kb = Qb + per4;
  uint4* Vb = Kb + per4;
  // ws needed: 3 * 16.78 MB = 50.3 MB

  proj_qkv<<<2048, 256, 0, stream>>>(x, Wq, Wk, Wv,
                                     (uint2*)Qb, (uint2*)Kb, (uint2*)Vb);
  attn_fused<<<512, 256, 0, stream>>>(Qb, Kb, Vb, out);
}

// Round 13
// 171.979 us; speedup vs baseline: 1.0790x; 1.0790x over previous
//
#include <hip/hip_runtime.h>

#define T_SEQ 2048
#define N_B   4
#define N_H   16
#define D_H   64
#define EMB   1024
#define CSC   0.18033688011f  // log2(e) / sqrt(64), folded into Q at projection

typedef __attribute__((ext_vector_type(8))) short   vshort8;   // 8 bf16 (4 VGPRs)
typedef __attribute__((ext_vector_type(4))) float   vfloat4;   // 16x16 C/D
typedef __attribute__((ext_vector_type(16))) float  vfloat16;  // 32x32 C/D

__device__ __forceinline__ ushort f2bf(float f) {
  union { float f; unsigned u; } v; v.f = f;
  unsigned u = v.u;
  return (ushort)((u + 0x7fffu + ((u >> 16) & 1u)) >> 16);  // RNE
}
__device__ __forceinline__ unsigned pk2bf(float a, float b) {  // [bf(a),bf(b)] in mem
  return (unsigned)f2bf(a) | ((unsigned)f2bf(b) << 16);
}
__device__ __forceinline__ float bf2f(ushort b) {
  union { unsigned u; float f; } v; v.u = ((unsigned)b) << 16;
  return v.f;
}
__device__ __forceinline__ float fexp2(float x) {
#if __has_builtin(__builtin_amdgcn_exp2f)
  return __builtin_amdgcn_exp2f(x);
#else
  return exp2f(x);
#endif
}
// pack hi16(lo),hi16(hi) -> [bf_trunc(lo), bf_trunc(hi)] in memory (1 v_perm)
__device__ __forceinline__ unsigned permhi(float hi, float lo) {
  union { float f; unsigned u; } a, b; a.f = hi; b.f = lo;
#if __has_builtin(__builtin_amdgcn_perm)
  return __builtin_amdgcn_perm(a.u, b.u, 0x07060302u);
#else
  return (a.u & 0xFFFF0000u) | (b.u >> 16);
#endif
}
__device__ __forceinline__ vshort8 cvt8(const float* p) {
  float4 w0 = *(const float4*)(p);
  float4 w1 = *(const float4*)(p + 4);
  vshort8 t;
  t[0] = (short)f2bf(w0.x); t[1] = (short)f2bf(w0.y);
  t[2] = (short)f2bf(w0.z); t[3] = (short)f2bf(w0.w);
  t[4] = (short)f2bf(w1.x); t[5] = (short)f2bf(w1.y);
  t[6] = (short)f2bf(w1.z); t[7] = (short)f2bf(w1.w);
  return t;
}

// ---- 32-lane-fragment blob layouts (uint4 = 8 bf16 = one lane-frag) ----
// Q/K: uint4 idx = ((bh*64 + t32)*4 + dstep)*64 + l31*2 + h
//      lane (l31,h) frag = X[t = 32*t32 + l31][d = 16*dstep + 8*h + 0..7]
// V  : uint4 idx = (((bh*32 + s64)*4 + step)*2 + dblk)*64 + l31*2 + h
//      lane (l31,h) frag = V[s = 64*s64 + 16*step + 8*h + 0..7][d = 32*dblk + l31]

// ------- QKV projection (16x16 MFMA compute, 32-frag stores) ---------------
// Round-9 version verbatim (best-total config, 172.1us).  W conversion
// fused in-kernel (r8: saved ~7.5us vs separate wconv kernel); r10 proved
// the uint2 store pattern is NOT a bottleneck (lane-permuted 8B stores
// within a 2KB window coalesce at cache-line level).
__global__ __launch_bounds__(256, 4) void proj_qkv(
    const float* __restrict__ x, const float* __restrict__ Wq,
    const float* __restrict__ Wk, const float* __restrict__ Wv,
    uint2* __restrict__ Qb, uint2* __restrict__ Kb, uint2* __restrict__ Vb) {
  const int wid  = threadIdx.x >> 6;
  const int lane = threadIdx.x & 63;
  const int l15  = lane & 15;
  const int q    = lane >> 4;
  const int gw    = blockIdx.x * 4 + wid;   // [0,8192)
  const int strip = gw >> 4;                // 16-row strip over B*T
  const int hd    = gw & 15;
  const int r0    = strip * 16;
  const int b     = r0 >> 11;
  const int bh    = b * N_H + hd;
  const int ts    = (r0 & (T_SEQ - 1)) >> 4;  // strip index within head [0,128)

  // ---- cooperative W conversion into LDS (layout == old Wb blob) ----
  __shared__ ushort Wl[24 * 64 * 8];   // 24 KB
#pragma unroll
  for (int fi = 0; fi < 6; ++fi) {
    const int f  = wid + fi * 4;             // frag group = (m*2+kc)*4+nt
    const int m  = f >> 3, kc = (f >> 2) & 1, nt = f & 3;
    const float* wsrc = (m == 0) ? Wq : (m == 1) ? Wk : Wv;
    vshort8 t = cvt8(wsrc + (nt * 16 + l15) * D_H + kc * 32 + q * 8);
    *(vshort8*)(&Wl[(f * 64 + lane) * 8]) = t;
  }

  // x frag: lane holds x[r0+l15][hd*64 + kc*32 + q*8 + j]
  vshort8 afr[2];
  {
    const float* xp = x + (size_t)(r0 + l15) * EMB + hd * D_H + q * 8;
    afr[0] = cvt8(xp);
    afr[1] = cvt8(xp + 32);
  }
  __syncthreads();                           // W fragments landed

  uint2* Bs[3] = {Qb, Kb, Vb};
#pragma unroll
  for (int m = 0; m < 3; ++m) {
    vshort8 wf[2][4];
#pragma unroll
    for (int kc = 0; kc < 2; ++kc)
#pragma unroll
      for (int nt = 0; nt < 4; ++nt)
        wf[kc][nt] = *(const vshort8*)(&Wl[(((m * 2 + kc) * 4 + nt) * 64 + lane) * 8]);
    vfloat4 acc[4];
#pragma unroll
    for (int nt = 0; nt < 4; ++nt) acc[nt] = (vfloat4){0.f, 0.f, 0.f, 0.f};
#pragma unroll
    for (int kc = 0; kc < 2; ++kc)
#pragma unroll
      for (int nt = 0; nt < 4; ++nt)
        acc[nt] = (m < 2)
          ? __builtin_amdgcn_mfma_f32_16x16x32_bf16(wf[kc][nt], afr[kc], acc[nt], 0, 0, 0)
          : __builtin_amdgcn_mfma_f32_16x16x32_bf16(afr[kc], wf[kc][nt], acc[nt], 0, 0, 0);
    uint2* B = Bs[m];
#pragma unroll
    for (int nt = 0; nt < 4; ++nt) {
      vfloat4 a = acc[nt];
      if (m == 0) { a[0] *= CSC; a[1] *= CSC; a[2] *= CSC; a[3] *= CSC; }
      uint2 w;
      w.x = pk2bf(a[0], a[1]);
      w.y = pk2bf(a[2], a[3]);
      size_t idx;
      if (m < 2) {
        // swapped C: lane holds (d = 16nt+4q+r, t = l15); t32 = ts>>1
        idx = ((size_t)(bh * 64 + (ts >> 1)) * 4 + nt) * 128
              + (l15 + 16 * (ts & 1)) * 4 + q;
      } else {
        // normal C: lane holds (s = 16(ts&3)+4q+r local in s64, d = 16nt+l15)
        idx = (((size_t)(bh * 32 + (ts >> 2)) * 4 + (ts & 3)) * 2 + (nt >> 1)) * 128
              + 64 * (nt & 1) + l15 * 4 + q;
      }
      B[idx] = w;
    }
  }
}

// ---------------- fused flash attention (no-max softmax) + V residual -------
// Round-0/round-9 inner loop VERBATIM (83.5-84.9us, 124 VGPR, zero scratch
// — reproduced 3x).  Wave = 64 q-rows, block = 4 waves of one (b,h), global
// K/V loads, zero LDS, zero barriers; waves drift freely and cover each
// other's stalls.  TERMINAL per 12 rounds of evidence: oacc+sacc fill the
// unified VGPR/AGPR file by construction (~100 accum + 124 arch at the
// 2-wave/SIMD cap).  Every modification spilled or lost: t-split(r1),
// s-split(r2/r3), vzero+ptr-bump+unroll2(r4), K-rotation(r5), K+V LDS
// stage(r6), K-only LDS stage(r7), plswap(r8,r11), setprio(r12 — even a
// register-FREE SOPP constrains the scheduler into +4 regs and spills),
// store-coalesce proj(r10, null).  Do not modify this kernel.
__global__ __launch_bounds__(256, 2) void attn_fused(
    const uint4* __restrict__ Qb, const uint4* __restrict__ Kb,
    const uint4* __restrict__ Vb, float* __restrict__ out) {
  const int tid  = threadIdx.x;
  const int wid  = tid >> 6;
  const int lane = tid & 63;
  const int l31  = lane & 31;
  const int h    = lane >> 5;

  // XCD swizzle: 16 consecutive per-XCD slots share a bh -> K/V stay in that L2
  const int blk  = blockIdx.x;                 // [0,512)
  const int work = (blk & 7) * 64 + (blk >> 3);
  const int bh   = work >> 3;
  const int tblk8 = work & 7;
  const int b = bh >> 4, hh = bh & 15;
  const int T64 = tblk8 * 4 + wid;             // this wave's 64-t chunk [0,32)

  const int lo = l31 * 2 + h;                  // lane offset in uint4 units

  // Q B-frags: lane holds Q[t = 32*t32 + l31][d = 16ds + 8h + j] * CSC
  vshort8 qf[2][4];
#pragma unroll
  for (int tb = 0; tb < 2; ++tb)
#pragma unroll
    for (int ds = 0; ds < 4; ++ds)
      qf[tb][ds] = *(const vshort8*)&Qb[((size_t)(bh * 64 + 2 * T64 + tb) * 4 + ds) * 64 + lo];

  vfloat16 oacc[2][2];
#pragma unroll
  for (int tb = 0; tb < 2; ++tb)
#pragma unroll
    for (int db = 0; db < 2; ++db)
#pragma unroll
      for (int i = 0; i < 16; ++i) oacc[tb][db][i] = 0.f;
  float lsum[2] = {0.f, 0.f};

#pragma unroll 1
  for (int ss = 0; ss < 32; ++ss) {  // 32 s-tiles of 64
    // K A-frags: lane holds K[s = 64ss + 32sb + l31][d = 16ds + 8h + j]
    vshort8 kf[2][4];
#pragma unroll
    for (int sb = 0; sb < 2; ++sb)
#pragma unroll
      for (int ds = 0; ds < 4; ++ds)
        kf[sb][ds] = *(const vshort8*)&Kb[((size_t)(bh * 64 + 2 * ss + sb) * 4 + ds) * 64 + lo];
    // V B-frags: lane holds V[s = 64ss + 16st + 8h + j][d = 32db + l31]
    vshort8 vf[4][2];
#pragma unroll
    for (int st = 0; st < 4; ++st)
#pragma unroll
      for (int db = 0; db < 2; ++db)
        vf[st][db] = *(const vshort8*)&Vb[(((size_t)(bh * 32 + ss) * 4 + st) * 2 + db) * 64 + lo];

#pragma unroll
    for (int tb = 0; tb < 2; ++tb) {
      // S^T = K*Q^T : C holds (s-local = (r&3)+8(r>>2)+4h + 32sb, t = l31)
      vfloat16 sacc[2];
#pragma unroll
      for (int sb = 0; sb < 2; ++sb) {
#pragma unroll
        for (int i = 0; i < 16; ++i) sacc[sb][i] = 0.f;
#pragma unroll
        for (int ds = 0; ds < 4; ++ds)
          sacc[sb] = __builtin_amdgcn_mfma_f32_32x32x16_bf16(kf[sb][ds], qf[tb][ds], sacc[sb], 0, 0, 0);
      }
      // no-max softmax + in-register C->A transpose of P
      float p[2][16];
      float ls = 0.f;
#pragma unroll
      for (int sb = 0; sb < 2; ++sb)
#pragma unroll
        for (int r = 0; r < 16; ++r) {
          p[sb][r] = fexp2(sacc[sb][r]);
          ls += p[sb][r];
        }
      lsum[tb] += ls;

#pragma unroll
      for (int sb = 0; sb < 2; ++sb)
#pragma unroll
        for (int g = 0; g < 2; ++g) {
          // own packs: OL = s 16g+4h+{0..3}, OH = s 16g+8+4h+{0..3} (local in sb)
          const unsigned OL0 = permhi(p[sb][8 * g + 1], p[sb][8 * g + 0]);
          const unsigned OL1 = permhi(p[sb][8 * g + 3], p[sb][8 * g + 2]);
          const unsigned OH0 = permhi(p[sb][8 * g + 5], p[sb][8 * g + 4]);
          const unsigned OH1 = permhi(p[sb][8 * g + 7], p[sb][8 * g + 6]);
          // exchange: h=0 needs partner's OL, h=1 needs partner's OH
          const unsigned s0 = h ? OL0 : OH0;
          const unsigned s1 = h ? OL1 : OH1;
          const unsigned r0 = (unsigned)__shfl_xor((int)s0, 32, 64);
          const unsigned r1 = (unsigned)__shfl_xor((int)s1, 32, 64);
          union { unsigned u[4]; vshort8 v; } pa;
          pa.u[0] = h ? r0 : OL0;
          pa.u[1] = h ? r1 : OL1;
          pa.u[2] = h ? OH0 : r0;
          pa.u[3] = h ? OH1 : r1;
          const int st = 2 * sb + g;
#pragma unroll
          for (int db = 0; db < 2; ++db)
            oacc[tb][db] = __builtin_amdgcn_mfma_f32_32x32x16_bf16(pa.v, vf[st][db], oacc[tb][db], 0, 0, 0);
        }
    }
  }

  // ---- epilogue: l-reduce, O/l + V residual ----
  const uint2* Vb2 = (const uint2*)Vb;
#pragma unroll
  for (int tb = 0; tb < 2; ++tb) {
    const float l = lsum[tb] + __shfl_xor(lsum[tb], 32, 64);
    const float inv = 1.0f / l;                // valid at t-local = l31
    const int T32 = 2 * T64 + tb;
#pragma unroll
    for (int db = 0; db < 2; ++db) {
#pragma unroll
      for (int rq = 0; rq < 4; ++rq) {
        const int sq = 8 * T32 + 2 * rq + h;   // t-quad (4 consecutive t)
        uint2 vr = Vb2[(((size_t)(bh * 32 + (sq >> 4)) * 4 + ((sq >> 2) & 3)) * 2 + db) * 128
                       + l31 * 4 + ((sq >> 1) & 1) * 2 + (sq & 1)];
        float vres[4];
        vres[0] = bf2f((ushort)(vr.x & 0xFFFFu));
        vres[1] = bf2f((ushort)(vr.x >> 16));
        vres[2] = bf2f((ushort)(vr.y & 0xFFFFu));
        vres[3] = bf2f((ushort)(vr.y >> 16));
#pragma unroll
        for (int rr = 0; rr < 4; ++rr) {
          const int row = rr + 8 * rq + 4 * h;          // t-local in [0,32)
          const float iT = __shfl(inv, row, 64);
          const int t = T32 * 32 + row;
          out[((size_t)(b * T_SEQ + t)) * EMB + hh * D_H + db * 32 + l31] =
              oacc[tb][db][rq * 4 + rr] * iT + vres[rr];
        }
      }
    }
  }
}

extern "C" void kernel_launch(void* const* d_in, const int* in_sizes, int n_in,
                              void* d_out, int out_size, void* d_ws, size_t ws_size,
                              hipStream_t stream) {
  const float* x  = (const float*)d_in[0];
  const float* Wq = (const float*)d_in[1];
  const float* Wk = (const float*)d_in[2];
  const float* Wv = (const float*)d_in[3];
  float* out = (float*)d_out;

  const size_t per4 = (size_t)64 * 64 * 4 * 64;  // 1,048,576 uint4 per blob (16 MB)
  uint4* Qb = (uint4*)d_ws;
  uint4* Kb = Qb + per4;
  uint4* Vb = Kb + per4;
  // ws needed: 3 * 16.78 MB = 50.3 MB

  proj_qkv<<<2048, 256, 0, stream>>>(x, Wq, Wk, Wv,
                                     (uint2*)Qb, (uint2*)Kb, (uint2*)Vb);
  attn_fused<<<512, 256, 0, stream>>>(Qb, Kb, Vb, out);
}